// Round 1
// baseline (3434.570 us; speedup 1.0000x reference)
//
#include <hip/hip_runtime.h>
#include <stdint.h>

// Problem constants
static constexpr int H_ = 200, W_ = 200, HW_ = 40000;
static constexpr int C_ = 512;
static constexpr int A_ = 9;
static constexpr int NANCH = 360000;   // HW_ * A_
static constexpr int KPRE = 1000;
static constexpr int KPOST = 100;

// ---------------------------------------------------------------------------
// K0: weight transpose  w[co][ci][tap] (512 x 4608) -> wt[k=ci*9+tap][co]
// ---------------------------------------------------------------------------
__global__ void k_transpose_w(const float* __restrict__ w, float* __restrict__ wt) {
    __shared__ float t[32][33];
    int kb = blockIdx.x * 32;   // k base (k-dim 4608 = 144*32)
    int cb = blockIdx.y * 32;   // co base (512 = 16*32)
    int lx = threadIdx.x;       // 0..31
    int ly = threadIdx.y;       // 0..7
    for (int r = ly; r < 32; r += 8)
        t[r][lx] = w[(cb + r) * 4608 + kb + lx];
    __syncthreads();
    for (int r = ly; r < 32; r += 8)
        wt[(size_t)(kb + r) * 512 + cb + lx] = t[lx][r];
}

// ---------------------------------------------------------------------------
// K1: 3x3 conv 512->512, SAME pad, + bias + ReLU.  fp32 vector FMA.
// Block tile: 128 co x (8x8 px). 256 threads, per-thread 8co x 4px.
// K-chunk: 4 input channels (all 9 taps).
// ---------------------------------------------------------------------------
__launch_bounds__(256, 6)
__global__ void k_conv3(const float* __restrict__ feat, const float* __restrict__ wt,
                        const float* __restrict__ bias, float* __restrict__ x) {
    __shared__ __align__(16) float wlds[4 * 9 * 128];  // [ci4][tap9][co128]
    __shared__ float ilds[4][10][10];                  // [ci4][row10][col10]

    int b = blockIdx.x;
    int cot = b & 3;
    int tile = b >> 2;            // 0..624
    int xt = tile % 25, yt = tile / 25;
    int x0 = xt * 8, y0 = yt * 8;
    int co0 = cot * 128;
    int tid = threadIdx.x;
    int tco = tid >> 4;           // 0..15 -> co = co0 + tco*8
    int tpx = tid & 15;
    int r = tpx >> 1;             // row 0..7
    int ch4 = (tpx & 1) * 4;      // col half 0 or 4

    float acc[8][4];
#pragma unroll
    for (int i = 0; i < 8; ++i)
#pragma unroll
        for (int j = 0; j < 4; ++j) acc[i][j] = 0.f;

    for (int ccb = 0; ccb < 512; ccb += 4) {
        // stage weights: 4*9*128 = 4608 floats = 1152 float4
        for (int t = tid; t < 1152; t += 256) {
            int u = t >> 5;               // local (ci*9+tap), 0..35
            int l = (t & 31) << 2;        // co offset
            float4 v = *(const float4*)&wt[(size_t)(ccb * 9 + u) * 512 + co0 + l];
            *(float4*)&wlds[u * 128 + l] = v;
        }
        // stage input: 4 * 10 * 10 = 400 floats (halo, zero-padded)
        for (int t = tid; t < 400; t += 256) {
            int ci = t / 100;
            int rem = t - ci * 100;
            int rr = rem / 10;
            int cc2 = rem - rr * 10;
            int gy = y0 - 1 + rr, gx = x0 - 1 + cc2;
            float v = 0.f;
            if ((unsigned)gy < (unsigned)H_ && (unsigned)gx < (unsigned)W_)
                v = feat[(size_t)(ccb + ci) * HW_ + gy * W_ + gx];
            ilds[ci][rr][cc2] = v;
        }
        __syncthreads();

#pragma unroll
        for (int ci = 0; ci < 4; ++ci) {
#pragma unroll
            for (int kh = 0; kh < 3; ++kh) {
                float iv[6];
#pragma unroll
                for (int c = 0; c < 6; ++c) iv[c] = ilds[ci][r + kh][ch4 + c];
#pragma unroll
                for (int kw = 0; kw < 3; ++kw) {
                    const float* wp = &wlds[(ci * 9 + kh * 3 + kw) * 128 + tco * 8];
                    float wv[8];
                    *(float4*)&wv[0] = *(const float4*)&wp[0];
                    *(float4*)&wv[4] = *(const float4*)&wp[4];
#pragma unroll
                    for (int i = 0; i < 8; ++i)
#pragma unroll
                        for (int j = 0; j < 4; ++j)
                            acc[i][j] = fmaf(wv[i], iv[kw + j], acc[i][j]);
                }
            }
        }
        __syncthreads();
    }

    // epilogue: bias + relu, float4 stores
    int gy = y0 + r;
#pragma unroll
    for (int i = 0; i < 8; ++i) {
        int co = co0 + tco * 8 + i;
        float bv = bias[co];
        float o[4];
#pragma unroll
        for (int j = 0; j < 4; ++j) {
            float v = acc[i][j] + bv;
            o[j] = v > 0.f ? v : 0.f;
        }
        *(float4*)&x[(size_t)co * HW_ + gy * W_ + x0 + ch4] = *(float4*)&o[0];
    }
}

// ---------------------------------------------------------------------------
// K2: cls 1x1 conv (512->9) + bias + sigmoid -> scores[p*9+a]
// ---------------------------------------------------------------------------
__global__ void k_cls(const float* __restrict__ xbuf, const float* __restrict__ cls_w,
                      const float* __restrict__ cls_b, float* __restrict__ scores) {
    __shared__ float wl[9 * 512];
    int tid = threadIdx.x;
    for (int t = tid; t < 9 * 512; t += 256) wl[t] = cls_w[t];
    __syncthreads();
    int p = blockIdx.x * 256 + tid;
    if (p >= HW_) return;
    float acc[9];
#pragma unroll
    for (int a = 0; a < 9; ++a) acc[a] = 0.f;
    for (int ci = 0; ci < C_; ++ci) {
        float xv = xbuf[(size_t)ci * HW_ + p];
#pragma unroll
        for (int a = 0; a < 9; ++a) acc[a] = fmaf(xv, wl[a * 512 + ci], acc[a]);
    }
#pragma unroll
    for (int a = 0; a < 9; ++a) {
        float lg = acc[a] + cls_b[a];
        scores[(size_t)p * 9 + a] = 1.f / (1.f + expf(-lg));
    }
}

// ---------------------------------------------------------------------------
// K3: exact top-1000 (radix select on float bits; ties -> smallest index)
// meta layout: [0]=P (hi16 prefix) [1]=countAboveP [2]=T (full bits)
//              [3]=cntGtT [4]=need(#eq to take) [8]=atomic cnt_gt [9]=atomic cnt_eq
// ---------------------------------------------------------------------------
__global__ void k_zero_u32(unsigned* __restrict__ p, int n) {
    int i = blockIdx.x * 256 + threadIdx.x;
    if (i < n) p[i] = 0u;
}

__global__ void k_hist1(const float* __restrict__ scores, unsigned* __restrict__ hist) {
    int i = blockIdx.x * 256 + threadIdx.x;
    if (i < NANCH) atomicAdd(&hist[__float_as_uint(scores[i]) >> 16], 1u);
}

__global__ void k_hist2(const float* __restrict__ scores, const unsigned* __restrict__ meta,
                        unsigned* __restrict__ hist2) {
    int i = blockIdx.x * 256 + threadIdx.x;
    if (i >= NANCH) return;
    unsigned b = __float_as_uint(scores[i]);
    if ((b >> 16) == meta[0]) atomicAdd(&hist2[b & 0xFFFFu], 1u);
}

// mode 0: hist over hi16, base=0 -> meta[0]=P, meta[1]=countAbove
// mode 1: hist over lo16 (prefix==P), base=meta[1] -> meta[2]=T, meta[3]=cntGt, meta[4]=need
__global__ void k_find_thr(const unsigned* __restrict__ hist, unsigned* __restrict__ meta, int mode) {
    __shared__ unsigned csum[1024];
    int t = threadIdx.x;
    unsigned base = (mode == 0) ? 0u : meta[1];
    unsigned s = 0;
    for (int b = 0; b < 64; ++b) s += hist[t * 64 + b];
    csum[t] = s;
    __syncthreads();
    // inclusive suffix sum: csum[t] = sum_{c>=t}
    for (int off = 1; off < 1024; off <<= 1) {
        unsigned add = (t + off < 1024) ? csum[t + off] : 0u;
        __syncthreads();
        csum[t] += add;
        __syncthreads();
    }
    unsigned run = base + ((t < 1023) ? csum[t + 1] : 0u);
    for (int b = 63; b >= 0; --b) {
        unsigned h = hist[t * 64 + b];
        if (run < (unsigned)KPRE && run + h >= (unsigned)KPRE) {
            if (mode == 0) {
                meta[0] = (unsigned)(t * 64 + b);
                meta[1] = run;
            } else {
                meta[2] = (meta[0] << 16) | (unsigned)(t * 64 + b);
                meta[3] = run;
                meta[4] = (unsigned)KPRE - run;
            }
            break;
        }
        run += h;
    }
}

__global__ void k_collect(const float* __restrict__ scores, unsigned* __restrict__ meta,
                          unsigned* __restrict__ sel_bits, unsigned* __restrict__ sel_idx,
                          unsigned* __restrict__ eq_idx) {
    int i = blockIdx.x * 256 + threadIdx.x;
    if (i >= NANCH) return;
    unsigned b = __float_as_uint(scores[i]);
    unsigned T = meta[2];
    if (b > T) {
        unsigned s = atomicAdd(&meta[8], 1u);
        sel_bits[s] = b;
        sel_idx[s] = (unsigned)i;
    } else if (b == T) {
        unsigned s = atomicAdd(&meta[9], 1u);
        eq_idx[s] = (unsigned)i;
    }
}

__global__ void k_topk_final(const unsigned* __restrict__ sel_bits, const unsigned* __restrict__ sel_idx,
                             const unsigned* __restrict__ eq_idx, const unsigned* __restrict__ meta,
                             unsigned* __restrict__ top_idx, float* __restrict__ top_sc) {
    __shared__ uint64_t keys[1024];
    __shared__ int lcnt;
    __shared__ int lred;
    int t = threadIdx.x;
    unsigned cntGt = meta[3];
    unsigned need = meta[4];
    unsigned cntEq = meta[9];
    unsigned T = meta[2];

    unsigned idx_cut = 0xFFFFFFFFu;
    if (cntEq > need) {
        // smallest m with count(eq_idx <= m) >= need
        unsigned lo = 0, hi = NANCH - 1;
        while (lo < hi) {
            unsigned mid = (lo + hi) >> 1;
            int c = 0;
            for (unsigned e = t; e < cntEq; e += 1024)
                if (eq_idx[e] <= mid) c++;
            if (t == 0) lred = 0;
            __syncthreads();
            atomicAdd(&lred, c);
            __syncthreads();
            int tot = lred;
            __syncthreads();
            if ((unsigned)tot >= need) hi = mid; else lo = mid + 1;
        }
        idx_cut = lo;
    }

    keys[t] = 0ull;
    if (t == 0) lcnt = 0;
    __syncthreads();
    for (unsigned s = t; s < cntGt; s += 1024)
        keys[s] = ((uint64_t)sel_bits[s] << 32) | (uint64_t)(0xFFFFFFFFu - sel_idx[s]);
    for (unsigned e = t; e < cntEq; e += 1024) {
        unsigned ix = eq_idx[e];
        if (ix <= idx_cut) {
            int s2 = (int)cntGt + atomicAdd(&lcnt, 1);
            keys[s2] = ((uint64_t)T << 32) | (uint64_t)(0xFFFFFFFFu - ix);
        }
    }
    __syncthreads();
    // bitonic sort, descending
    for (int k = 2; k <= 1024; k <<= 1) {
        for (int j = k >> 1; j > 0; j >>= 1) {
            int ixj = t ^ j;
            if (ixj > t) {
                uint64_t a = keys[t], b = keys[ixj];
                bool desc = (t & k) == 0;
                if (desc ? (a < b) : (a > b)) { keys[t] = b; keys[ixj] = a; }
            }
            __syncthreads();
        }
    }
    if (t < KPRE) {
        top_sc[t] = __uint_as_float((unsigned)(keys[t] >> 32));
        top_idx[t] = 0xFFFFFFFFu - (unsigned)keys[t];
    }
}

// ---------------------------------------------------------------------------
// K4: reg head for the 1000 selected + decode + clamp; one block (64 thr) each
// ---------------------------------------------------------------------------
__global__ void k_decode(const float* __restrict__ xbuf, const float* __restrict__ reg_w,
                         const float* __restrict__ reg_b, const unsigned* __restrict__ top_idx,
                         float* __restrict__ props, float* __restrict__ areas) {
    int j = blockIdx.x;
    int lane = threadIdx.x;  // 64
    unsigned idx = top_idx[j];
    int pix = (int)(idx / 9u);
    int a = (int)(idx - (unsigned)pix * 9u);
    float s0 = 0, s1 = 0, s2 = 0, s3 = 0;
    for (int c = lane; c < C_; c += 64) {
        float xv = xbuf[(size_t)c * HW_ + pix];
        s0 = fmaf(xv, reg_w[(a * 4 + 0) * C_ + c], s0);
        s1 = fmaf(xv, reg_w[(a * 4 + 1) * C_ + c], s1);
        s2 = fmaf(xv, reg_w[(a * 4 + 2) * C_ + c], s2);
        s3 = fmaf(xv, reg_w[(a * 4 + 3) * C_ + c], s3);
    }
#pragma unroll
    for (int o = 32; o > 0; o >>= 1) {
        s0 += __shfl_down(s0, o);
        s1 += __shfl_down(s1, o);
        s2 += __shfl_down(s2, o);
        s3 += __shfl_down(s3, o);
    }
    if (lane == 0) {
        float d0 = s0 + reg_b[a * 4 + 0];
        float d1 = s1 + reg_b[a * 4 + 1];
        float d2 = s2 + reg_b[a * 4 + 2];
        float d3 = s3 + reg_b[a * 4 + 3];
        int h = pix / W_, w2 = pix - h * W_;
        int rr = a / 3, ss = a - rr * 3;
        float ratio = (rr == 0) ? 0.5f : (rr == 1) ? 1.0f : 2.0f;
        float scale = (ss == 0) ? 128.f : (ss == 1) ? 256.f : 512.f;
        float hr = sqrtf(ratio);
        float wr = 1.0f / hr;
        float wsc = wr * scale, hsc = hr * scale;
        float sx = (float)w2 * 16.f, sy = (float)h * 16.f;
        float a0 = sx - wsc * 0.5f, a1 = sy - hsc * 0.5f;
        float a2 = sx + wsc * 0.5f, a3 = sy + hsc * 0.5f;
        float bw = a2 - a0, bh = a3 - a1;
        float cx = a0 + 0.5f * bw, cy = a1 + 0.5f * bh;
        float px = d0 * bw + cx, py = d1 * bh + cy;
        float pw = expf(d2) * bw, ph = expf(d3) * bh;
        float b0 = px - 0.5f * pw, b1 = py - 0.5f * ph;
        float b2 = px + 0.5f * pw, b3 = py + 0.5f * ph;
        b0 = fminf(fmaxf(b0, 0.f), 3200.f);
        b1 = fminf(fmaxf(b1, 0.f), 3200.f);
        b2 = fminf(fmaxf(b2, 0.f), 3200.f);
        b3 = fminf(fmaxf(b3, 0.f), 3200.f);
        props[j * 4 + 0] = b0;
        props[j * 4 + 1] = b1;
        props[j * 4 + 2] = b2;
        props[j * 4 + 3] = b3;
        areas[j] = (b2 - b0) * (b3 - b1);
    }
}

// ---------------------------------------------------------------------------
// K5: NMS suppression bitmask (1000 x 16 words); block i vs all j
// ---------------------------------------------------------------------------
__global__ void k_nms_mask(const float* __restrict__ props, const float* __restrict__ areas,
                           unsigned long long* __restrict__ mask, float* __restrict__ out) {
    int i = blockIdx.x;
    int tid = threadIdx.x;  // 256
    if (i == 0) {
        for (int t = tid; t < KPOST * 5; t += 256) out[t] = 0.f;
    }
    float x1i = props[i * 4 + 0], y1i = props[i * 4 + 1];
    float x2i = props[i * 4 + 2], y2i = props[i * 4 + 3];
    float ai = areas[i];
#pragma unroll
    for (int k = 0; k < 4; ++k) {
        int j = k * 256 + tid;
        bool sup = false;
        if (j < KPRE && j > i) {
            float iw = fminf(x2i, props[j * 4 + 2]) - fmaxf(x1i, props[j * 4 + 0]);
            float ih = fminf(y2i, props[j * 4 + 3]) - fmaxf(y1i, props[j * 4 + 1]);
            iw = fmaxf(iw, 0.f);
            ih = fmaxf(ih, 0.f);
            float inter = iw * ih;
            float iou = inter / (ai + areas[j] - inter);
            sup = iou > 0.7f;
        }
        unsigned long long b = __ballot(sup);
        int word = k * 4 + (tid >> 6);
        if ((tid & 63) == 0) mask[(size_t)i * 16 + word] = b;
    }
}

// ---------------------------------------------------------------------------
// K6: serial NMS scan over bitmask + compact first 100 kept -> output
// single wave (64 threads); lanes 0..15 own the 16 keep words
// ---------------------------------------------------------------------------
__global__ void k_nms_scan_out(const unsigned long long* __restrict__ mask,
                               const float* __restrict__ props, const float* __restrict__ top_sc,
                               float* __restrict__ out) {
    int lane = threadIdx.x;  // 64
    unsigned long long keep = 0ull;
    if (lane < 16) keep = (lane < 15) ? ~0ull : ((1ull << 40) - 1);  // 1000 bits
    for (int i = 0; i < KPRE; ++i) {
        unsigned long long kw = __shfl(keep, i >> 6);
        if ((kw >> (i & 63)) & 1ull) {
            if (lane < 16) keep &= ~mask[(size_t)i * 16 + lane];
        }
    }
    int pcv = (lane < 16) ? (int)__popcll(keep) : 0;
    int pre = 0;
    for (int j = 0; j < 16; ++j) {
        int v = __shfl(pcv, j);
        if (j < lane) pre += v;
    }
    for (int w = 0; w < 16; ++w) {
        unsigned long long kw = __shfl(keep, w);
        int base = __shfl(pre, w);
        int idx = w * 64 + lane;
        if (idx < KPRE && ((kw >> lane) & 1ull)) {
            int rank = base + (int)__popcll(kw & ((1ull << lane) - 1ull));
            if (rank < KPOST) {
                out[rank * 4 + 0] = props[idx * 4 + 0];
                out[rank * 4 + 1] = props[idx * 4 + 1];
                out[rank * 4 + 2] = props[idx * 4 + 2];
                out[rank * 4 + 3] = props[idx * 4 + 3];
                out[KPOST * 4 + rank] = top_sc[idx];
            }
        }
    }
}

// ---------------------------------------------------------------------------
extern "C" void kernel_launch(void* const* d_in, const int* in_sizes, int n_in,
                              void* d_out, int out_size, void* d_ws, size_t ws_size,
                              hipStream_t stream) {
    const float* feat   = (const float*)d_in[0];
    const float* conv_w = (const float*)d_in[1];
    const float* conv_b = (const float*)d_in[2];
    const float* cls_w  = (const float*)d_in[3];
    const float* cls_b  = (const float*)d_in[4];
    const float* reg_w  = (const float*)d_in[5];
    const float* reg_b  = (const float*)d_in[6];
    float* out = (float*)d_out;

    // workspace bump allocator (256B aligned)
    size_t off = 0;
    auto alloc = [&](size_t bytes) -> void* {
        off = (off + 255) & ~(size_t)255;
        void* p = (char*)d_ws + off;
        off += bytes;
        return p;
    };
    float* wt      = (float*)alloc((size_t)4608 * 512 * 4);       // 9.44 MB
    float* xbuf    = (float*)alloc((size_t)C_ * HW_ * 4);         // 81.9 MB
    float* scores  = (float*)alloc((size_t)NANCH * 4);            // 1.44 MB
    unsigned* hist1 = (unsigned*)alloc(65536 * 4);
    unsigned* hist2 = (unsigned*)alloc(65536 * 4);
    unsigned* meta  = (unsigned*)alloc(64 * 4);
    unsigned* sel_bits = (unsigned*)alloc(1024 * 4);
    unsigned* sel_idx  = (unsigned*)alloc(1024 * 4);
    unsigned* eq_idx   = (unsigned*)alloc((size_t)NANCH * 4);     // 1.44 MB
    unsigned* top_idx  = (unsigned*)alloc(KPRE * 4);
    float* top_sc      = (float*)alloc(KPRE * 4);
    float* props       = (float*)alloc(KPRE * 4 * 4);
    float* areas       = (float*)alloc(KPRE * 4);
    unsigned long long* mask = (unsigned long long*)alloc((size_t)KPRE * 16 * 8);
    (void)ws_size; (void)in_sizes; (void)n_in; (void)out_size;

    // 0) transpose weights
    k_transpose_w<<<dim3(144, 16), dim3(32, 8), 0, stream>>>(conv_w, wt);
    // 1) conv 3x3 + bias + relu
    k_conv3<<<2500, 256, 0, stream>>>(feat, wt, conv_b, xbuf);
    // 2) cls head + sigmoid
    k_cls<<<(HW_ + 255) / 256, 256, 0, stream>>>(xbuf, cls_w, cls_b, scores);
    // 3) top-1000 radix select (hist1/hist2/meta are contiguous: zero in one go)
    k_zero_u32<<<(65536 * 2 + 64 + 255) / 256, 256, 0, stream>>>(hist1, 65536 * 2 + 64);
    k_hist1<<<(NANCH + 255) / 256, 256, 0, stream>>>(scores, hist1);
    k_find_thr<<<1, 1024, 0, stream>>>(hist1, meta, 0);
    k_hist2<<<(NANCH + 255) / 256, 256, 0, stream>>>(scores, meta, hist2);
    k_find_thr<<<1, 1024, 0, stream>>>(hist2, meta, 1);
    k_collect<<<(NANCH + 255) / 256, 256, 0, stream>>>(scores, meta, sel_bits, sel_idx, eq_idx);
    k_topk_final<<<1, 1024, 0, stream>>>(sel_bits, sel_idx, eq_idx, meta, top_idx, top_sc);
    // 4) reg head + decode + clamp for selected
    k_decode<<<KPRE, 64, 0, stream>>>(xbuf, reg_w, reg_b, top_idx, props, areas);
    // 5) NMS mask (+ zero d_out)
    k_nms_mask<<<KPRE, 256, 0, stream>>>(props, areas, mask, out);
    // 6) NMS scan + compact to outputs
    k_nms_scan_out<<<1, 64, 0, stream>>>(mask, props, top_sc, out);
}